// Round 11
// baseline (13531.976 us; speedup 1.0000x reference)
//
#include <hip/hip_runtime.h>
#include <math.h>

#define TT 2048
#define NB 64
#define EE 256
#define HH 256
#define PJ 16    // j-partitions recorded in part[] (unchanged layout)
#define XLD 288  // swizzled row: 256 + 4 pad per 32 floats
#define RS1 280  // red_s kc stride
#define RS2 72   // red_s batch stride
#define RBOFF (8 * RS1)   // context-B offset within red_s

typedef float f32x4 __attribute__((ext_vector_type(4)));

__device__ __forceinline__ float sigf(float x) { return 1.f / (1.f + expf(-x)); }

__device__ __forceinline__ unsigned long long packh(unsigned tag, float v) {
    union { float f; unsigned u; } c; c.f = v;
    return ((unsigned long long)tag << 32) | (unsigned long long)c.u;
}

// R16: R14 dual-context stagger + dedicated SERVICE WAVE (wv8, 576 threads).
// R14's epilogue waves (wv0/wv1) ran epilogue + full FMA share between
// barriers -> arrived ~450cy late at B1b/B2b -> ~900cy/step barrier skew.
// wv8 does no FMA: epilogue A runs during others' phase1_B, epilogue B(t-1)
// during next step's phase1_A, part-sums in the idle phase2_A window. Spin
// duty perfectly balanced: A-spin waves 0-3, B-spin waves 4-7 (each compute
// wave spins exactly once/step). red_s layout reverted to R14's float2-write/
// scalar-read (R15's transpose was an 8-way write conflict, +75% LDS
// conflicts). A-tags pre-issued at loop top; B-tags after B1a (h_B publish
// happens during phase1_A -> earlier would be stale). Staging wv4-7 loop-top
// issue as R14. All fp op orders / transported bits identical to R14.
__global__ __launch_bounds__(576, 2)
void lstm_kernel(const int* __restrict__ sent, const float* __restrict__ emb,
                 const float* __restrict__ W_ih, const float* __restrict__ W_hh,
                 const float* __restrict__ b_ih, const float* __restrict__ b_hh,
                 const float* __restrict__ W_z,
                 unsigned long long* __restrict__ hbuf,
                 float* __restrict__ part)
{
    __shared__ __align__(16) float x_sw[4 * XLD];   // rows 0-1: A, 2-3: B
    __shared__ __align__(16) float h_sw[4 * XLD];
    __shared__ __align__(16) float red_s[2 * 8 * RS1];
    __shared__ __align__(16) float p_s[64];         // 0-31: A, 32-63: B
    extern __shared__ float dyn_pad[];              // occupancy pad

    const int tid  = threadIdx.x;
    if (tid == 0 && sent[0] < 0) ((volatile float*)dyn_pad)[0] = 0.f;

    // XCD-clustering swizzle (heuristic)
    const int xcd  = blockIdx.x & 7;
    const int slot = blockIdx.x >> 3;        // 0..31
    const int psys = xcd * 2 + (slot >> 4);  // 0..15 pair-system
    const int js   = slot & 15;              // j-slice
    const int bA0  = psys * 2;
    const int bB0  = 32 + psys * 2;
    const int j0   = js * 16;

    const int wv    = tid >> 6;              // 0..8
    const int lane  = tid & 63;
    const bool isComp = (wv < 8);
    const bool isSvc  = (wv == 8);

    const int bp    = wv & 1;                // batch within context
    const int kc    = ((wv & 7) >> 1) * 2 + (lane & 1);  // 0..7 k-chunk
    const int rg    = lane >> 1;             // 0..31 row-group (2 rows)
    const int kbase = kc << 5;

    // ---- weights -> VGPRs (compute waves only): 128 VGPRs ----
    float4 wih_r[16], whh_r[16];
    if (isComp) {
        #pragma unroll
        for (int i = 0; i < 2; ++i) {
            int lr = rg * 2 + i;
            long grow = (long)((lr >> 4) * HH + j0 + (lr & 15));
            const float4* wi = (const float4*)(W_ih + grow * EE + kbase);
            const float4* wh = (const float4*)(W_hh + grow * EE + kbase);
            #pragma unroll
            for (int mi = 0; mi < 8; ++mi) {
                wih_r[i * 8 + mi] = wi[mi];
                whh_r[i * 8 + mi] = wh[mi];
            }
        }
    }

    // ---- service-wave epilogue state: lanes 0-31 -> A, lanes 32-63 -> B ----
    const int eb  = (lane >> 4) & 1;  // batch 0..1 within context
    const int ejj = lane & 15;
    float bias_g[4]; float wz_r = 0.f; float c_reg = 0.f;
    if (isSvc) {
        #pragma unroll
        for (int g = 0; g < 4; ++g)
            bias_g[g] = b_ih[g * HH + j0 + ejj] + b_hh[g * HH + j0 + ejj];
        wz_r = W_z[j0 + ejj];
    }

    // ---- spin mappings (2 tagged words/thread, balanced) ----
    const bool spinA = (wv < 4);
    const bool spinB = (wv >= 4 && wv < 8);
    const int aidx = ((wv & 3) << 6) + lane;   // 0..255 (valid if spinA)
    const int bidx = ((wv & 3) << 6) + lane;   // 0..255 (valid if spinB)
    const int acb = aidx >> 7, acw = (aidx & 127) << 1;
    const int bcb = bidx >> 7, bcw = (bidx & 127) << 1;
    const int acph = acw + ((acw >> 5) << 2);
    const int bcph = bcw + ((bcw >> 5) << 2);

    // ---- staging: wv4,5 -> A rows 0,1 ; wv6,7 -> B rows 2,3 ----
    const bool stgA = (wv == 4 || wv == 5);
    const bool stgB = (wv == 6 || wv == 7);
    const int srow  = (wv >= 6 ? 2 : 0) + bp;
    const int sphys = 4 * lane + ((lane >> 3) << 2);
    int tok_st = 0;

    if (stgA || stgB) {   // prologue: stage x(0) for both contexts
        int base = stgA ? bA0 : bB0;
        int tk0 = sent[0 * NB + base + bp];
        f32x4 xv0 = ((const f32x4*)(emb + (long)tk0 * EE))[lane];
        *(f32x4*)(&x_sw[srow * XLD + sphys]) = xv0;
        tok_st = sent[1 * NB + base + bp];
    }
    __syncthreads();

    for (int t = 0; t < TT; ++t) {
        const bool pf = (t + 1 < TT);
        const size_t parIn  = (size_t)(((t - 1) & 1) * NB);
        const size_t parOut = (size_t)((t & 1) * NB);
        const unsigned want = (unsigned)t;

        // ---- loop top (phase1_A window) ----
        f32x4 xst;
        if ((stgA || stgB) && pf) {   // staging emb issue (long cover)
            xst = ((const f32x4*)(emb + (long)tok_st * EE))[lane];
            if (t + 2 < TT)
                tok_st = sent[(t + 2) * NB + (stgA ? bA0 : bB0) + bp];
        }
        unsigned long long a0 = 0, a1 = 0, b0v = 0, b1v = 0;
        unsigned long long* hpA = hbuf + (parIn + bA0 + acb) * HH + acw;
        unsigned long long* hpB = hbuf + (parIn + bB0 + bcb) * HH + bcw;
        if (t > 0 && spinA) {   // A-tag pre-issue (publish was ~a half ago)
            a0 = __hip_atomic_load(hpA + 0, __ATOMIC_RELAXED, __HIP_MEMORY_SCOPE_AGENT);
            a1 = __hip_atomic_load(hpA + 1, __ATOMIC_RELAXED, __HIP_MEMORY_SCOPE_AGENT);
        }
        if (t > 0 && isSvc && lane >= 32) {   // epilogue B(t-1)
            float sg[4];
            #pragma unroll
            for (int g = 0; g < 4; ++g) {
                float s = bias_g[g];
                #pragma unroll
                for (int k2 = 0; k2 < 8; ++k2)
                    s += red_s[RBOFF + k2 * RS1 + eb * RS2 + g * 16 + ejj];
                sg[g] = s;
            }
            float cn = sigf(sg[1]) * c_reg + sigf(sg[0]) * tanhf(sg[2]);
            float hn = sigf(sg[3]) * tanhf(cn);
            c_reg = cn;
            p_s[lane] = hn * wz_r;
            __hip_atomic_store(
                hbuf + (parIn + bB0 + eb) * HH + j0 + ejj,
                packh(want, hn),
                __ATOMIC_RELAXED, __HIP_MEMORY_SCOPE_AGENT);
        }

        // ---- phase 1 A: x partials ----
        float4 acc[2];
        acc[0] = make_float4(0.f, 0.f, 0.f, 0.f);
        acc[1] = make_float4(0.f, 0.f, 0.f, 0.f);
        if (isComp) {
            const float* xb = &x_sw[bp * XLD + kc * 36];
            #pragma unroll
            for (int mi = 0; mi < 8; ++mi) {
                float4 xv4 = *(const float4*)(xb + mi * 4);
                #pragma unroll
                for (int i = 0; i < 2; ++i) {
                    float4 w = wih_r[i * 8 + mi];
                    acc[i].x += w.x * xv4.x; acc[i].y += w.y * xv4.y;
                    acc[i].z += w.z * xv4.z; acc[i].w += w.w * xv4.w;
                }
            }
        }
        if (t > 0 && spinA) {   // A-check
            while ((unsigned)(a0 >> 32) != want)
                a0 = __hip_atomic_load(hpA + 0, __ATOMIC_RELAXED, __HIP_MEMORY_SCOPE_AGENT);
            while ((unsigned)(a1 >> 32) != want)
                a1 = __hip_atomic_load(hpA + 1, __ATOMIC_RELAXED, __HIP_MEMORY_SCOPE_AGENT);
            union { unsigned u; float f; } c0, c1;
            c0.u = (unsigned)a0; c1.u = (unsigned)a1;
            *(float2*)(&h_sw[acb * XLD + acph]) = make_float2(c0.f, c1.f);
        }
        __syncthreads();   // B1a: h_A ready; x_A(t) reads done

        if (t > 0 && isSvc && lane < 4) {   // part-sums (t-1), idle window
            int b = lane & 1;
            float s = 0.f;
            if (lane < 2) {
                #pragma unroll
                for (int jj = 0; jj < 16; ++jj) s += p_s[b * 16 + jj];
                part[((size_t)(t - 1) * PJ + js) * NB + bA0 + b] = s;
            } else {
                #pragma unroll
                for (int jj = 0; jj < 16; ++jj) s += p_s[32 + b * 16 + jj];
                part[((size_t)(t - 1) * PJ + js) * NB + bB0 + b] = s;
            }
        }
        if (t > 0 && spinB) {   // B-tag pre-issue (publish was in phase1_A)
            b0v = __hip_atomic_load(hpB + 0, __ATOMIC_RELAXED, __HIP_MEMORY_SCOPE_AGENT);
            b1v = __hip_atomic_load(hpB + 1, __ATOMIC_RELAXED, __HIP_MEMORY_SCOPE_AGENT);
        }
        if (isComp && t > 0) {   // phase 2 A: h partials
            const float* hb = &h_sw[bp * XLD + kc * 36];
            #pragma unroll
            for (int mi = 0; mi < 8; ++mi) {
                float4 hv4 = *(const float4*)(hb + mi * 4);
                #pragma unroll
                for (int i = 0; i < 2; ++i) {
                    float4 w = whh_r[i * 8 + mi];
                    acc[i].x += w.x * hv4.x; acc[i].y += w.y * hv4.y;
                    acc[i].z += w.z * hv4.z; acc[i].w += w.w * hv4.w;
                }
            }
        }
        if (isComp) {   // horizontal add -> red_s A (R14 layout, float2)
            float2 v;
            v.x = (acc[0].x + acc[0].y) + (acc[0].z + acc[0].w);
            v.y = (acc[1].x + acc[1].y) + (acc[1].z + acc[1].w);
            *(float2*)(&red_s[kc * RS1 + bp * RS2 + rg * 2]) = v;
        }
        if (stgA && pf) {   // stage x_A(t+1)
            *(f32x4*)(&x_sw[srow * XLD + sphys]) = xst;
        }
        __syncthreads();   // B2a: red_A ready; x_A staged

        if (isSvc && lane < 32) {   // epilogue A(t), overlaps phase1_B
            float sg[4];
            #pragma unroll
            for (int g = 0; g < 4; ++g) {
                float s = bias_g[g];
                #pragma unroll
                for (int k2 = 0; k2 < 8; ++k2)
                    s += red_s[k2 * RS1 + eb * RS2 + g * 16 + ejj];
                sg[g] = s;
            }
            float cn = sigf(sg[1]) * c_reg + sigf(sg[0]) * tanhf(sg[2]);
            float hn = sigf(sg[3]) * tanhf(cn);
            c_reg = cn;
            p_s[lane] = hn * wz_r;
            __hip_atomic_store(
                hbuf + (parOut + bA0 + eb) * HH + j0 + ejj,
                packh((unsigned)(t + 1), hn),
                __ATOMIC_RELAXED, __HIP_MEMORY_SCOPE_AGENT);
        }

        // ---- phase 1 B: x partials ----
        acc[0] = make_float4(0.f, 0.f, 0.f, 0.f);
        acc[1] = make_float4(0.f, 0.f, 0.f, 0.f);
        if (isComp) {
            const float* xb = &x_sw[(2 + bp) * XLD + kc * 36];
            #pragma unroll
            for (int mi = 0; mi < 8; ++mi) {
                float4 xv4 = *(const float4*)(xb + mi * 4);
                #pragma unroll
                for (int i = 0; i < 2; ++i) {
                    float4 w = wih_r[i * 8 + mi];
                    acc[i].x += w.x * xv4.x; acc[i].y += w.y * xv4.y;
                    acc[i].z += w.z * xv4.z; acc[i].w += w.w * xv4.w;
                }
            }
        }
        if (t > 0 && spinB) {   // B-check
            while ((unsigned)(b0v >> 32) != want)
                b0v = __hip_atomic_load(hpB + 0, __ATOMIC_RELAXED, __HIP_MEMORY_SCOPE_AGENT);
            while ((unsigned)(b1v >> 32) != want)
                b1v = __hip_atomic_load(hpB + 1, __ATOMIC_RELAXED, __HIP_MEMORY_SCOPE_AGENT);
            union { unsigned u; float f; } c0, c1;
            c0.u = (unsigned)b0v; c1.u = (unsigned)b1v;
            *(float2*)(&h_sw[(2 + bcb) * XLD + bcph]) = make_float2(c0.f, c1.f);
        }
        __syncthreads();   // B1b: h_B ready; x_B(t) reads done

        if (isComp && t > 0) {   // phase 2 B: h partials
            const float* hb = &h_sw[(2 + bp) * XLD + kc * 36];
            #pragma unroll
            for (int mi = 0; mi < 8; ++mi) {
                float4 hv4 = *(const float4*)(hb + mi * 4);
                #pragma unroll
                for (int i = 0; i < 2; ++i) {
                    float4 w = whh_r[i * 8 + mi];
                    acc[i].x += w.x * hv4.x; acc[i].y += w.y * hv4.y;
                    acc[i].z += w.z * hv4.z; acc[i].w += w.w * hv4.w;
                }
            }
        }
        if (isComp) {   // horizontal add -> red_s B
            float2 v;
            v.x = (acc[0].x + acc[0].y) + (acc[0].z + acc[0].w);
            v.y = (acc[1].x + acc[1].y) + (acc[1].z + acc[1].w);
            *(float2*)(&red_s[RBOFF + kc * RS1 + bp * RS2 + rg * 2]) = v;
        }
        if (stgB && pf) {   // stage x_B(t+1)
            *(f32x4*)(&x_sw[srow * XLD + sphys]) = xst;
        }
        __syncthreads();   // B2b: red_B ready; x_B staged
        // epilogue B(t) runs at the next iteration's loop top (or post-loop)
    }

    // ---- post-loop: epilogue B(TT-1) (no publish needed) + final parts ----
    if (isSvc && lane >= 32) {
        float sg[4];
        #pragma unroll
        for (int g = 0; g < 4; ++g) {
            float s = bias_g[g];
            #pragma unroll
            for (int k2 = 0; k2 < 8; ++k2)
                s += red_s[RBOFF + k2 * RS1 + eb * RS2 + g * 16 + ejj];
            sg[g] = s;
        }
        float cn = sigf(sg[1]) * c_reg + sigf(sg[0]) * tanhf(sg[2]);
        float hn = sigf(sg[3]) * tanhf(cn);
        p_s[lane] = hn * wz_r;
    }
    __syncthreads();
    if (isSvc && lane < 4) {
        int b = lane & 1;
        float s = 0.f;
        if (lane < 2) {
            #pragma unroll
            for (int jj = 0; jj < 16; ++jj) s += p_s[b * 16 + jj];
            part[((size_t)(TT - 1) * PJ + js) * NB + bA0 + b] = s;
        } else {
            #pragma unroll
            for (int jj = 0; jj < 16; ++jj) s += p_s[32 + b * 16 + jj];
            part[((size_t)(TT - 1) * PJ + js) * NB + bB0 + b] = s;
        }
    }
}

__global__ void pz_kernel(const float* __restrict__ part,
                          const float* __restrict__ noise,
                          const float* __restrict__ b_z,
                          float* __restrict__ out)
{
    int idx = blockIdx.x * blockDim.x + threadIdx.x;  // t*64 + b
    if (idx >= TT * NB) return;
    int t = idx >> 6, b = idx & 63;
    float s = b_z[0];
    #pragma unroll
    for (int jg = 0; jg < PJ; ++jg) s += part[(t * PJ + jg) * NB + b];
    float pz = 1.f / (1.f + expf(-s));
    out[idx] = pz;
    out[TT * NB + idx] = (noise[idx] < pz) ? 1.f : 0.f;
}

// One block per batch column: stable compaction of tokens where z==1.
__global__ void compact_kernel(const int* __restrict__ sent,
                               const float* __restrict__ zbuf,
                               float* __restrict__ rat,
                               float* __restrict__ zsz)
{
    __shared__ float rat_s[TT];
    __shared__ int scan_s[256];
    int b = blockIdx.x, tid = threadIdx.x;
    int zloc[8];
    int base = tid * 8;
    int c = 0;
    #pragma unroll
    for (int i = 0; i < 8; ++i) {
        zloc[i] = (zbuf[(base + i) * NB + b] != 0.f) ? 1 : 0;
        c += zloc[i];
    }
    scan_s[tid] = c;
    for (int i = tid; i < TT; i += 256) rat_s[i] = 0.f;
    __syncthreads();
    for (int off = 1; off < 256; off <<= 1) {
        int v = scan_s[tid];
        int add = (tid >= off) ? scan_s[tid - off] : 0;
        __syncthreads();
        scan_s[tid] = v + add;
        __syncthreads();
    }
    int total = scan_s[255];
    int pos = scan_s[tid] - c;  // exclusive prefix
    #pragma unroll
    for (int i = 0; i < 8; ++i) {
        if (zloc[i]) { rat_s[pos] = (float)sent[(base + i) * NB + b]; ++pos; }
    }
    __syncthreads();
    for (int i = tid; i < TT; i += 256) rat[i * NB + b] = rat_s[i];
    if (tid == 0) zsz[b] = (float)total;
}

extern "C" void kernel_launch(void* const* d_in, const int* in_sizes, int n_in,
                              void* d_out, int out_size, void* d_ws, size_t ws_size,
                              hipStream_t stream)
{
    const int*   sent  = (const int*)d_in[0];
    const float* noise = (const float*)d_in[1];
    const float* emb   = (const float*)d_in[2];
    const float* W_ih  = (const float*)d_in[3];
    const float* W_hh  = (const float*)d_in[4];
    const float* b_ih  = (const float*)d_in[5];
    const float* b_hh  = (const float*)d_in[6];
    const float* W_z   = (const float*)d_in[7];
    const float* b_z   = (const float*)d_in[8];
    float* out = (float*)d_out;

    char* ws = (char*)d_ws;
    unsigned long long* hbuf = (unsigned long long*)ws;     // 2*64*256*8 = 256 KB
    float* part = (float*)(ws + 262144);                    // 2048*16*64*4 = 8 MB

    // tags must start != any expected tag (1..2048)
    (void)hipMemsetAsync(hbuf, 0, 2 * NB * HH * sizeof(unsigned long long), stream);

    // ~27.4KB static + 64KB dynamic -> ~91KB -> exactly 1 WG/CU
    lstm_kernel<<<256, 576, 65536, stream>>>(sent, emb, W_ih, W_hh, b_ih, b_hh,
                                             W_z, hbuf, part);
    pz_kernel<<<(TT * NB) / 256, 256, 0, stream>>>(part, noise, b_z, out);
    compact_kernel<<<NB, 256, 0, stream>>>(sent, out + TT * NB,
                                           out + 2 * TT * NB, out + 3 * TT * NB);
}

// Round 12
// 5280.798 us; speedup vs baseline: 2.5625x; 2.5625x over previous
//
#include <hip/hip_runtime.h>
#include <math.h>

#define TT 2048
#define NB 64
#define EE 256
#define HH 256
#define PJ 16    // j-partitions recorded in part[] (unchanged layout)
#define XLD 288  // swizzled row: 256 + 4 pad per 32 floats
#define RS1 280  // red_s kc stride
#define RS2 72   // red_s batch stride
#define RBOFF (8 * RS1)   // context-B offset within red_s

typedef float f32x4 __attribute__((ext_vector_type(4)));

__device__ __forceinline__ float sigf(float x) { return 1.f / (1.f + expf(-x)); }

__device__ __forceinline__ unsigned long long packh(unsigned tag, float v) {
    union { float f; unsigned u; } c; c.f = v;
    return ((unsigned long long)tag << 32) | (unsigned long long)c.u;
}

// R17: R14 (champion, 4545us dispatch) + the two SAFE R15 edits only:
//  1. Balanced spins: A-spin waves 0-3, B-spin waves 4-7 (R14's wv4/wv7
//     double duty removed). 2. Tag pre-issue: A-tags at loop top (publish
//     ~2000cy earlier -> fresh, L2 latency hidden under phase1_A); B-tags
//     after B1a (publish >=1500cy earlier, checked ~1000cy later).
//  3. Staging on wv4-7 only, all issued at loop top (their spin checks are
//     >=1500cy after issue -> no drain exposure).
// R15's red_s transpose is REVERTED (it was an 8-way LDS write conflict,
// +75% SQ_LDS_BANK_CONFLICT). R16's service wave is dead: conditional
// weight arrays spilled to scratch (VGPR 84, +53MB writes). Weights stay
// unconditional on all waves. All fp op orders / transported bits
// identical to R14 (bitwise outputs, absmax 0).
__global__ __launch_bounds__(512, 2)
void lstm_kernel(const int* __restrict__ sent, const float* __restrict__ emb,
                 const float* __restrict__ W_ih, const float* __restrict__ W_hh,
                 const float* __restrict__ b_ih, const float* __restrict__ b_hh,
                 const float* __restrict__ W_z,
                 unsigned long long* __restrict__ hbuf,
                 float* __restrict__ part)
{
    __shared__ __align__(16) float x_sw[4 * XLD];   // rows 0-1: A, 2-3: B
    __shared__ __align__(16) float h_sw[4 * XLD];
    __shared__ __align__(16) float red_s[2 * 8 * RS1];
    __shared__ __align__(16) float p_s[64];         // 0-31: A, 32-63: B
    extern __shared__ float dyn_pad[];              // occupancy pad

    const int tid  = threadIdx.x;
    if (tid == 0 && sent[0] < 0) ((volatile float*)dyn_pad)[0] = 0.f;

    // XCD-clustering swizzle (heuristic)
    const int xcd  = blockIdx.x & 7;
    const int slot = blockIdx.x >> 3;        // 0..31
    const int psys = xcd * 2 + (slot >> 4);  // 0..15 pair-system
    const int js   = slot & 15;              // j-slice
    const int bA0  = psys * 2;
    const int bB0  = 32 + psys * 2;
    const int j0   = js * 16;

    const int wv    = tid >> 6;              // 0..7
    const int lane  = tid & 63;
    const int bp    = wv & 1;                // batch within context
    const int kc    = (wv >> 1) * 2 + (lane & 1);  // 0..7 k-chunk
    const int rg    = lane >> 1;             // 0..31 row-group (2 rows)
    const int kbase = kc << 5;

    // ---- weights -> VGPRs (ALL waves, unconditional): 128 VGPRs ----
    float4 wih_r[16], whh_r[16];
    #pragma unroll
    for (int i = 0; i < 2; ++i) {
        int lr = rg * 2 + i;
        long grow = (long)((lr >> 4) * HH + j0 + (lr & 15));
        const float4* wi = (const float4*)(W_ih + grow * EE + kbase);
        const float4* wh = (const float4*)(W_hh + grow * EE + kbase);
        #pragma unroll
        for (int mi = 0; mi < 8; ++mi) {
            wih_r[i * 8 + mi] = wi[mi];
            whh_r[i * 8 + mi] = wh[mi];
        }
    }

    // ---- epilogue state: wv0 -> A, wv1 -> B (lanes 0..31) ----
    const int eb  = (lane >> 4) & 1;  // batch 0..1 within context
    const int ejj = lane & 15;
    float bias_g[4]; float wz_r = 0.f; float c_reg = 0.f;
    if (wv < 2) {
        #pragma unroll
        for (int g = 0; g < 4; ++g)
            bias_g[g] = b_ih[g * HH + j0 + ejj] + b_hh[g * HH + j0 + ejj];
        wz_r = W_z[j0 + ejj];
    }

    // ---- spin mappings (2 tagged words/thread, perfectly balanced) ----
    const bool spinA = (wv < 4);
    const bool spinB = (wv >= 4);
    const int sidx = ((wv & 3) << 6) + lane;   // 0..255
    const int scb  = sidx >> 7;                // batch within context
    const int scw  = (sidx & 127) << 1;        // even word index
    const int scph = scw + ((scw >> 5) << 2);  // swizzled LDS offset

    // ---- staging: wv4,5 -> A rows 0,1 ; wv6,7 -> B rows 2,3 ----
    const bool stgA = (wv == 4 || wv == 5);
    const int srow  = (wv >= 6 ? 2 : 0) + bp;
    const int sphys = 4 * lane + ((lane >> 3) << 2);
    int tok_st = 0;

    if (wv >= 4) {   // prologue: stage x(0) for both contexts
        int base = stgA ? bA0 : bB0;
        int tk0 = sent[0 * NB + base + bp];
        f32x4 xv0 = ((const f32x4*)(emb + (long)tk0 * EE))[lane];
        *(f32x4*)(&x_sw[srow * XLD + sphys]) = xv0;
        tok_st = sent[1 * NB + base + bp];
    }
    __syncthreads();

    for (int t = 0; t < TT; ++t) {
        const bool pf = (t + 1 < TT);
        const size_t parIn  = (size_t)(((t - 1) & 1) * NB);
        const size_t parOut = (size_t)((t & 1) * NB);
        const unsigned want = (unsigned)t;

        // ---- loop top: staging emb issue + A-tag pre-issue ----
        f32x4 xst;
        if (wv >= 4 && pf) {
            xst = ((const f32x4*)(emb + (long)tok_st * EE))[lane];
            if (t + 2 < TT)
                tok_st = sent[(t + 2) * NB + (stgA ? bA0 : bB0) + bp];
        }
        unsigned long long v0 = 0, v1 = 0;
        unsigned long long* hpA = hbuf + (parIn + bA0 + scb) * HH + scw;
        unsigned long long* hpB = hbuf + (parIn + bB0 + scb) * HH + scw;
        if (t > 0 && spinA) {   // A-tags: publish was a B-half ago -> fresh
            v0 = __hip_atomic_load(hpA + 0, __ATOMIC_RELAXED, __HIP_MEMORY_SCOPE_AGENT);
            v1 = __hip_atomic_load(hpA + 1, __ATOMIC_RELAXED, __HIP_MEMORY_SCOPE_AGENT);
        }

        // ================= A half =================
        float4 acc[2];
        acc[0] = make_float4(0.f, 0.f, 0.f, 0.f);
        acc[1] = make_float4(0.f, 0.f, 0.f, 0.f);
        {   // phase 1: x partials
            const float* xb = &x_sw[bp * XLD + kc * 36];
            #pragma unroll
            for (int mi = 0; mi < 8; ++mi) {
                float4 xv4 = *(const float4*)(xb + mi * 4);
                #pragma unroll
                for (int i = 0; i < 2; ++i) {
                    float4 w = wih_r[i * 8 + mi];
                    acc[i].x += w.x * xv4.x; acc[i].y += w.y * xv4.y;
                    acc[i].z += w.z * xv4.z; acc[i].w += w.w * xv4.w;
                }
            }
        }
        if (t > 0 && spinA) {   // A-check (loads already in flight)
            while ((unsigned)(v0 >> 32) != want)
                v0 = __hip_atomic_load(hpA + 0, __ATOMIC_RELAXED, __HIP_MEMORY_SCOPE_AGENT);
            while ((unsigned)(v1 >> 32) != want)
                v1 = __hip_atomic_load(hpA + 1, __ATOMIC_RELAXED, __HIP_MEMORY_SCOPE_AGENT);
            union { unsigned u; float f; } c0, c1;
            c0.u = (unsigned)v0; c1.u = (unsigned)v1;
            *(float2*)(&h_sw[scb * XLD + scph]) = make_float2(c0.f, c1.f);
        }
        __syncthreads();   // B1a: h_A ready; x_A(t) reads done

        if (t > 0 && wv == 2 && lane < 2) {   // part A(t-1)
            float s = 0.f;
            #pragma unroll
            for (int jj = 0; jj < 16; ++jj) s += p_s[lane * 16 + jj];
            part[((size_t)(t - 1) * PJ + js) * NB + bA0 + lane] = s;
        }
        if (t > 0 && spinB) {   // B-tag pre-issue (publish >=1500cy ago)
            v0 = __hip_atomic_load(hpB + 0, __ATOMIC_RELAXED, __HIP_MEMORY_SCOPE_AGENT);
            v1 = __hip_atomic_load(hpB + 1, __ATOMIC_RELAXED, __HIP_MEMORY_SCOPE_AGENT);
        }
        if (t > 0) {   // phase 2: h partials
            const float* hb = &h_sw[bp * XLD + kc * 36];
            #pragma unroll
            for (int mi = 0; mi < 8; ++mi) {
                float4 hv4 = *(const float4*)(hb + mi * 4);
                #pragma unroll
                for (int i = 0; i < 2; ++i) {
                    float4 w = whh_r[i * 8 + mi];
                    acc[i].x += w.x * hv4.x; acc[i].y += w.y * hv4.y;
                    acc[i].z += w.z * hv4.z; acc[i].w += w.w * hv4.w;
                }
            }
        }
        {   // horizontal add -> red_s (A region, R14 layout)
            float2 v;
            v.x = (acc[0].x + acc[0].y) + (acc[0].z + acc[0].w);
            v.y = (acc[1].x + acc[1].y) + (acc[1].z + acc[1].w);
            *(float2*)(&red_s[kc * RS1 + bp * RS2 + rg * 2]) = v;
        }
        if (stgA && pf) {   // stage x_A(t+1)
            *(f32x4*)(&x_sw[srow * XLD + sphys]) = xst;
        }
        __syncthreads();   // B2a: red_A ready; x_A staged

        if (wv == 0 && lane < 32) {   // epilogue A + publish
            float sg[4];
            #pragma unroll
            for (int g = 0; g < 4; ++g) {
                float s = bias_g[g];
                #pragma unroll
                for (int k2 = 0; k2 < 8; ++k2)
                    s += red_s[k2 * RS1 + eb * RS2 + g * 16 + ejj];
                sg[g] = s;
            }
            float cn = sigf(sg[1]) * c_reg + sigf(sg[0]) * tanhf(sg[2]);
            float hn = sigf(sg[3]) * tanhf(cn);
            c_reg = cn;
            p_s[lane] = hn * wz_r;
            __hip_atomic_store(
                hbuf + (parOut + bA0 + eb) * HH + j0 + ejj,
                packh((unsigned)(t + 1), hn),
                __ATOMIC_RELAXED, __HIP_MEMORY_SCOPE_AGENT);
        }

        // ================= B half =================
        acc[0] = make_float4(0.f, 0.f, 0.f, 0.f);
        acc[1] = make_float4(0.f, 0.f, 0.f, 0.f);
        {   // phase 1: x partials
            const float* xb = &x_sw[(2 + bp) * XLD + kc * 36];
            #pragma unroll
            for (int mi = 0; mi < 8; ++mi) {
                float4 xv4 = *(const float4*)(xb + mi * 4);
                #pragma unroll
                for (int i = 0; i < 2; ++i) {
                    float4 w = wih_r[i * 8 + mi];
                    acc[i].x += w.x * xv4.x; acc[i].y += w.y * xv4.y;
                    acc[i].z += w.z * xv4.z; acc[i].w += w.w * xv4.w;
                }
            }
        }
        if (t > 0 && spinB) {   // B-check (loads long in flight)
            while ((unsigned)(v0 >> 32) != want)
                v0 = __hip_atomic_load(hpB + 0, __ATOMIC_RELAXED, __HIP_MEMORY_SCOPE_AGENT);
            while ((unsigned)(v1 >> 32) != want)
                v1 = __hip_atomic_load(hpB + 1, __ATOMIC_RELAXED, __HIP_MEMORY_SCOPE_AGENT);
            union { unsigned u; float f; } c0, c1;
            c0.u = (unsigned)v0; c1.u = (unsigned)v1;
            *(float2*)(&h_sw[(2 + scb) * XLD + scph]) = make_float2(c0.f, c1.f);
        }
        __syncthreads();   // B1b: h_B ready; x_B(t) reads done

        if (t > 0 && wv == 3 && lane < 2) {   // part B(t-1)
            float s = 0.f;
            #pragma unroll
            for (int jj = 0; jj < 16; ++jj) s += p_s[32 + lane * 16 + jj];
            part[((size_t)(t - 1) * PJ + js) * NB + bB0 + lane] = s;
        }
        if (t > 0) {   // phase 2: h partials
            const float* hb = &h_sw[(2 + bp) * XLD + kc * 36];
            #pragma unroll
            for (int mi = 0; mi < 8; ++mi) {
                float4 hv4 = *(const float4*)(hb + mi * 4);
                #pragma unroll
                for (int i = 0; i < 2; ++i) {
                    float4 w = whh_r[i * 8 + mi];
                    acc[i].x += w.x * hv4.x; acc[i].y += w.y * hv4.y;
                    acc[i].z += w.z * hv4.z; acc[i].w += w.w * hv4.w;
                }
            }
        }
        {   // horizontal add -> red_s (B region, R14 layout)
            float2 v;
            v.x = (acc[0].x + acc[0].y) + (acc[0].z + acc[0].w);
            v.y = (acc[1].x + acc[1].y) + (acc[1].z + acc[1].w);
            *(float2*)(&red_s[RBOFF + kc * RS1 + bp * RS2 + rg * 2]) = v;
        }
        if (!stgA && wv >= 4 && pf) {   // stage x_B(t+1)
            *(f32x4*)(&x_sw[srow * XLD + sphys]) = xst;
        }
        __syncthreads();   // B2b: red_B ready; x_B staged

        if (wv == 1 && lane < 32) {   // epilogue B + publish
            float sg[4];
            #pragma unroll
            for (int g = 0; g < 4; ++g) {
                float s = bias_g[g];
                #pragma unroll
                for (int k2 = 0; k2 < 8; ++k2)
                    s += red_s[RBOFF + k2 * RS1 + eb * RS2 + g * 16 + ejj];
                sg[g] = s;
            }
            float cn = sigf(sg[1]) * c_reg + sigf(sg[0]) * tanhf(sg[2]);
            float hn = sigf(sg[3]) * tanhf(cn);
            c_reg = cn;
            p_s[32 + lane] = hn * wz_r;
            __hip_atomic_store(
                hbuf + (parOut + bB0 + eb) * HH + j0 + ejj,
                packh((unsigned)(t + 1), hn),
                __ATOMIC_RELAXED, __HIP_MEMORY_SCOPE_AGENT);
        }
    }

    // final part-sums (t = TT-1)
    __syncthreads();
    if (wv == 2 && lane < 2) {
        float s = 0.f;
        #pragma unroll
        for (int jj = 0; jj < 16; ++jj) s += p_s[lane * 16 + jj];
        part[((size_t)(TT - 1) * PJ + js) * NB + bA0 + lane] = s;
    }
    if (wv == 3 && lane < 2) {
        float s = 0.f;
        #pragma unroll
        for (int jj = 0; jj < 16; ++jj) s += p_s[32 + lane * 16 + jj];
        part[((size_t)(TT - 1) * PJ + js) * NB + bB0 + lane] = s;
    }
}

__global__ void pz_kernel(const float* __restrict__ part,
                          const float* __restrict__ noise,
                          const float* __restrict__ b_z,
                          float* __restrict__ out)
{
    int idx = blockIdx.x * blockDim.x + threadIdx.x;  // t*64 + b
    if (idx >= TT * NB) return;
    int t = idx >> 6, b = idx & 63;
    float s = b_z[0];
    #pragma unroll
    for (int jg = 0; jg < PJ; ++jg) s += part[(t * PJ + jg) * NB + b];
    float pz = 1.f / (1.f + expf(-s));
    out[idx] = pz;
    out[TT * NB + idx] = (noise[idx] < pz) ? 1.f : 0.f;
}

// One block per batch column: stable compaction of tokens where z==1.
__global__ void compact_kernel(const int* __restrict__ sent,
                               const float* __restrict__ zbuf,
                               float* __restrict__ rat,
                               float* __restrict__ zsz)
{
    __shared__ float rat_s[TT];
    __shared__ int scan_s[256];
    int b = blockIdx.x, tid = threadIdx.x;
    int zloc[8];
    int base = tid * 8;
    int c = 0;
    #pragma unroll
    for (int i = 0; i < 8; ++i) {
        zloc[i] = (zbuf[(base + i) * NB + b] != 0.f) ? 1 : 0;
        c += zloc[i];
    }
    scan_s[tid] = c;
    for (int i = tid; i < TT; i += 256) rat_s[i] = 0.f;
    __syncthreads();
    for (int off = 1; off < 256; off <<= 1) {
        int v = scan_s[tid];
        int add = (tid >= off) ? scan_s[tid - off] : 0;
        __syncthreads();
        scan_s[tid] = v + add;
        __syncthreads();
    }
    int total = scan_s[255];
    int pos = scan_s[tid] - c;  // exclusive prefix
    #pragma unroll
    for (int i = 0; i < 8; ++i) {
        if (zloc[i]) { rat_s[pos] = (float)sent[(base + i) * NB + b]; ++pos; }
    }
    __syncthreads();
    for (int i = tid; i < TT; i += 256) rat[i * NB + b] = rat_s[i];
    if (tid == 0) zsz[b] = (float)total;
}

extern "C" void kernel_launch(void* const* d_in, const int* in_sizes, int n_in,
                              void* d_out, int out_size, void* d_ws, size_t ws_size,
                              hipStream_t stream)
{
    const int*   sent  = (const int*)d_in[0];
    const float* noise = (const float*)d_in[1];
    const float* emb   = (const float*)d_in[2];
    const float* W_ih  = (const float*)d_in[3];
    const float* W_hh  = (const float*)d_in[4];
    const float* b_ih  = (const float*)d_in[5];
    const float* b_hh  = (const float*)d_in[6];
    const float* W_z   = (const float*)d_in[7];
    const float* b_z   = (const float*)d_in[8];
    float* out = (float*)d_out;

    char* ws = (char*)d_ws;
    unsigned long long* hbuf = (unsigned long long*)ws;     // 2*64*256*8 = 256 KB
    float* part = (float*)(ws + 262144);                    // 2048*16*64*4 = 8 MB

    // tags must start != any expected tag (1..2048)
    (void)hipMemsetAsync(hbuf, 0, 2 * NB * HH * sizeof(unsigned long long), stream);

    // ~27KB static + 64KB dynamic -> ~91KB -> exactly 1 WG/CU
    lstm_kernel<<<256, 512, 65536, stream>>>(sent, emb, W_ih, W_hh, b_ih, b_hh,
                                             W_z, hbuf, part);
    pz_kernel<<<(TT * NB) / 256, 256, 0, stream>>>(part, noise, b_z, out);
    compact_kernel<<<NB, 256, 0, stream>>>(sent, out + TT * NB,
                                           out + 2 * TT * NB, out + 3 * TT * NB);
}

// Round 13
// 4287.925 us; speedup vs baseline: 3.1558x; 1.2316x over previous
//
#include <hip/hip_runtime.h>
#include <math.h>

#define TT 2048
#define NB 64
#define EE 256
#define HH 256
#define PJ 16    // j-partitions recorded in part[] (unchanged layout)
#define XLD 288  // swizzled row: 256 + 4 pad per 32 floats
#define RS1 280  // red_s kc stride
#define RS2 72   // red_s batch stride
#define RBOFF (8 * RS1)   // context-B offset within red_s

typedef float f32x4 __attribute__((ext_vector_type(4)));

__device__ __forceinline__ float sigf(float x) { return 1.f / (1.f + expf(-x)); }

__device__ __forceinline__ unsigned long long packh(unsigned tag, float v) {
    union { float f; unsigned u; } c; c.f = v;
    return ((unsigned long long)tag << 32) | (unsigned long long)c.u;
}

// R18: R14 dual-context stagger with barriers 4 -> 2 via SELF-SUFFICIENT
// spins. Each wave polls exactly the 64 h-words (1/lane, own batch bp,
// own 2 kc chunks) that it alone consumes, fills only its own h_sw region,
// and reads it back after lgkmcnt (same-wave order; no barrier). 8 waves x
// 64 lanes = all 512 words, zero redundancy; serial poll chain 2 -> 1.
// Schedule: [A window: phase1_A | self-spin A | phase2_A | red_A] S1
// [B window: wv0 epilogue_A overlapped | phase1_B | self-spin B | phase2_B
// | red_B | staging] S2 [tail: wv1 epilogue_B overlapped with next A].
// x_B double-buffered by parity (no barrier between phase1_B reads and
// x_B(t+1) write). Epilogue waves wv0/wv1 carry no staging (R17 lesson:
// keep gating waves light). All fp op orders / transported bits identical
// to R14 (bitwise outputs, absmax 0).
__global__ __launch_bounds__(512, 2)
void lstm_kernel(const int* __restrict__ sent, const float* __restrict__ emb,
                 const float* __restrict__ W_ih, const float* __restrict__ W_hh,
                 const float* __restrict__ b_ih, const float* __restrict__ b_hh,
                 const float* __restrict__ W_z,
                 unsigned long long* __restrict__ hbuf,
                 float* __restrict__ part)
{
    __shared__ __align__(16) float x_sw[6 * XLD]; // 0-1: A; 2-3: B par0; 4-5: B par1
    __shared__ __align__(16) float h_sw[4 * XLD]; // 0-1: A; 2-3: B
    __shared__ __align__(16) float red_s[2 * 8 * RS1];
    __shared__ __align__(16) float p_s[64];       // 0-31: A, 32-63: B
    extern __shared__ float dyn_pad[];            // occupancy pad

    const int tid  = threadIdx.x;
    if (tid == 0 && sent[0] < 0) ((volatile float*)dyn_pad)[0] = 0.f;

    // XCD-clustering swizzle (heuristic)
    const int xcd  = blockIdx.x & 7;
    const int slot = blockIdx.x >> 3;        // 0..31
    const int psys = xcd * 2 + (slot >> 4);  // 0..15 pair-system
    const int js   = slot & 15;              // j-slice
    const int bA0  = psys * 2;
    const int bB0  = 32 + psys * 2;
    const int j0   = js * 16;

    const int wv    = tid >> 6;              // 0..7
    const int lane  = tid & 63;
    const int bp    = wv & 1;                // batch within context
    const int kc    = (wv >> 1) * 2 + (lane & 1);  // 0..7 k-chunk
    const int rg    = lane >> 1;             // 0..31 row-group (2 rows)
    const int kbase = kc << 5;

    // ---- weights -> VGPRs (ALL waves, unconditional): 128 VGPRs ----
    float4 wih_r[16], whh_r[16];
    #pragma unroll
    for (int i = 0; i < 2; ++i) {
        int lr = rg * 2 + i;
        long grow = (long)((lr >> 4) * HH + j0 + (lr & 15));
        const float4* wi = (const float4*)(W_ih + grow * EE + kbase);
        const float4* wh = (const float4*)(W_hh + grow * EE + kbase);
        #pragma unroll
        for (int mi = 0; mi < 8; ++mi) {
            wih_r[i * 8 + mi] = wi[mi];
            whh_r[i * 8 + mi] = wh[mi];
        }
    }

    // ---- epilogue state: wv0 -> A, wv1 -> B (lanes 0..31) ----
    const int eb  = (lane >> 4) & 1;  // batch 0..1 within context
    const int ejj = lane & 15;
    float bias_g[4]; float wz_r = 0.f; float c_reg = 0.f;
    if (wv < 2) {
        #pragma unroll
        for (int g = 0; g < 4; ++g)
            bias_g[g] = b_ih[g * HH + j0 + ejj] + b_hh[g * HH + j0 + ejj];
        wz_r = W_z[j0 + ejj];
    }

    // ---- self-spin mapping: lane polls ONE word = h[bp][kc*32 + (lane>>1)]
    const int pj    = (kc << 5) + (lane >> 1);   // word index in batch row
    const int pphys = kc * 36 + (lane >> 1);     // swizzled offset in h_sw row

    // ---- staging: wv4,5 -> A rows 0,1 ; wv6,7 -> B parity rows ----
    const bool stgA = (wv == 4 || wv == 5);
    const bool stgB = (wv == 6 || wv == 7);
    const int sphys = 4 * lane + ((lane >> 3) << 2);
    int tok_st = 0;

    if (stgA || stgB) {   // prologue: stage x(0); B goes to parity 0
        int base = stgA ? bA0 : bB0;
        int tk0 = sent[0 * NB + base + bp];
        f32x4 xv0 = ((const f32x4*)(emb + (long)tk0 * EE))[lane];
        int row = stgA ? bp : (2 + bp);
        *(f32x4*)(&x_sw[row * XLD + sphys]) = xv0;
        tok_st = sent[1 * NB + base + bp];
    }
    __syncthreads();

    for (int t = 0; t < TT; ++t) {
        const bool pf = (t + 1 < TT);
        const size_t parIn  = (size_t)(((t - 1) & 1) * NB);
        const size_t parOut = (size_t)((t & 1) * NB);
        const unsigned want = (unsigned)t;

        // ================= A window =================
        f32x4 xst;
        if ((stgA || stgB) && pf) {   // staging emb issue (cover >= 1 window)
            xst = ((const f32x4*)(emb + (long)tok_st * EE))[lane];
            if (t + 2 < TT)
                tok_st = sent[(t + 2) * NB + (stgA ? bA0 : bB0) + bp];
        }
        unsigned long long* hpA = hbuf + (parIn + bA0 + bp) * HH + pj;
        unsigned long long pv = 0;
        if (t > 0)   // own A-tag pre-issue (hidden under phase1_A)
            pv = __hip_atomic_load(hpA, __ATOMIC_RELAXED, __HIP_MEMORY_SCOPE_AGENT);

        if (t > 0 && wv == 2 && lane < 2) {   // part A(t-1)
            float s = 0.f;
            #pragma unroll
            for (int jj = 0; jj < 16; ++jj) s += p_s[lane * 16 + jj];
            part[((size_t)(t - 1) * PJ + js) * NB + bA0 + lane] = s;
        }

        float4 acc[2];
        acc[0] = make_float4(0.f, 0.f, 0.f, 0.f);
        acc[1] = make_float4(0.f, 0.f, 0.f, 0.f);
        {   // phase 1 A: x partials
            const float* xb = &x_sw[bp * XLD + kc * 36];
            #pragma unroll
            for (int mi = 0; mi < 8; ++mi) {
                float4 xv4 = *(const float4*)(xb + mi * 4);
                #pragma unroll
                for (int i = 0; i < 2; ++i) {
                    float4 w = wih_r[i * 8 + mi];
                    acc[i].x += w.x * xv4.x; acc[i].y += w.y * xv4.y;
                    acc[i].z += w.z * xv4.z; acc[i].w += w.w * xv4.w;
                }
            }
        }
        if (t > 0) {   // self-spin A: check own word, fill own h_sw slot
            while ((unsigned)(pv >> 32) != want)
                pv = __hip_atomic_load(hpA, __ATOMIC_RELAXED, __HIP_MEMORY_SCOPE_AGENT);
            union { unsigned u; float f; } cu; cu.u = (unsigned)pv;
            h_sw[bp * XLD + pphys] = cu.f;
            // phase 2 A: h partials (same-wave fill -> lgkmcnt only)
            const float* hb = &h_sw[bp * XLD + kc * 36];
            #pragma unroll
            for (int mi = 0; mi < 8; ++mi) {
                float4 hv4 = *(const float4*)(hb + mi * 4);
                #pragma unroll
                for (int i = 0; i < 2; ++i) {
                    float4 w = whh_r[i * 8 + mi];
                    acc[i].x += w.x * hv4.x; acc[i].y += w.y * hv4.y;
                    acc[i].z += w.z * hv4.z; acc[i].w += w.w * hv4.w;
                }
            }
        }
        {   // red_A write (R14 layout)
            float2 v;
            v.x = (acc[0].x + acc[0].y) + (acc[0].z + acc[0].w);
            v.y = (acc[1].x + acc[1].y) + (acc[1].z + acc[1].w);
            *(float2*)(&red_s[kc * RS1 + bp * RS2 + rg * 2]) = v;
        }
        __syncthreads();   // S1: red_A ready; x_B(t) reads will start

        // ================= B window =================
        unsigned long long* hpB = hbuf + (parIn + bB0 + bp) * HH + pj;
        unsigned long long qv = 0;
        if (t > 0)   // own B-tag pre-issue (publish was in t-1's tail)
            qv = __hip_atomic_load(hpB, __ATOMIC_RELAXED, __HIP_MEMORY_SCOPE_AGENT);

        if (wv == 0 && lane < 32) {   // epilogue A(t): overlaps others' phase1_B
            float sg[4];
            #pragma unroll
            for (int g = 0; g < 4; ++g) {
                float s = bias_g[g];
                #pragma unroll
                for (int k2 = 0; k2 < 8; ++k2)
                    s += red_s[k2 * RS1 + eb * RS2 + g * 16 + ejj];
                sg[g] = s;
            }
            float cn = sigf(sg[1]) * c_reg + sigf(sg[0]) * tanhf(sg[2]);
            float hn = sigf(sg[3]) * tanhf(cn);
            c_reg = cn;
            p_s[lane] = hn * wz_r;
            __hip_atomic_store(
                hbuf + (parOut + bA0 + eb) * HH + j0 + ejj,
                packh((unsigned)(t + 1), hn),
                __ATOMIC_RELAXED, __HIP_MEMORY_SCOPE_AGENT);
        }
        if (t > 0 && wv == 3 && lane < 2) {   // part B(t-1)
            float s = 0.f;
            #pragma unroll
            for (int jj = 0; jj < 16; ++jj) s += p_s[32 + lane * 16 + jj];
            part[((size_t)(t - 1) * PJ + js) * NB + bB0 + lane] = s;
        }

        acc[0] = make_float4(0.f, 0.f, 0.f, 0.f);
        acc[1] = make_float4(0.f, 0.f, 0.f, 0.f);
        {   // phase 1 B: x partials (parity buffer)
            const float* xb = &x_sw[(2 + 2 * (t & 1) + bp) * XLD + kc * 36];
            #pragma unroll
            for (int mi = 0; mi < 8; ++mi) {
                float4 xv4 = *(const float4*)(xb + mi * 4);
                #pragma unroll
                for (int i = 0; i < 2; ++i) {
                    float4 w = wih_r[i * 8 + mi];
                    acc[i].x += w.x * xv4.x; acc[i].y += w.y * xv4.y;
                    acc[i].z += w.z * xv4.z; acc[i].w += w.w * xv4.w;
                }
            }
        }
        if (t > 0) {   // self-spin B + fill + phase 2 B
            while ((unsigned)(qv >> 32) != want)
                qv = __hip_atomic_load(hpB, __ATOMIC_RELAXED, __HIP_MEMORY_SCOPE_AGENT);
            union { unsigned u; float f; } cu; cu.u = (unsigned)qv;
            h_sw[(2 + bp) * XLD + pphys] = cu.f;
            const float* hb = &h_sw[(2 + bp) * XLD + kc * 36];
            #pragma unroll
            for (int mi = 0; mi < 8; ++mi) {
                float4 hv4 = *(const float4*)(hb + mi * 4);
                #pragma unroll
                for (int i = 0; i < 2; ++i) {
                    float4 w = whh_r[i * 8 + mi];
                    acc[i].x += w.x * hv4.x; acc[i].y += w.y * hv4.y;
                    acc[i].z += w.z * hv4.z; acc[i].w += w.w * hv4.w;
                }
            }
        }
        {   // red_B write
            float2 v;
            v.x = (acc[0].x + acc[0].y) + (acc[0].z + acc[0].w);
            v.y = (acc[1].x + acc[1].y) + (acc[1].z + acc[1].w);
            *(float2*)(&red_s[RBOFF + kc * RS1 + bp * RS2 + rg * 2]) = v;
        }
        if (stgA && pf)   // x_A(t+1): readers were pre-S1; next read post-S2
            *(f32x4*)(&x_sw[bp * XLD + sphys]) = xst;
        if (stgB && pf)   // x_B(t+1) into the OTHER parity buffer
            *(f32x4*)(&x_sw[(2 + 2 * ((t + 1) & 1) + bp) * XLD + sphys]) = xst;
        __syncthreads();   // S2: red_B ready; x staged

        // ================= tail: epilogue B(t), overlaps next A window ====
        if (wv == 1 && lane < 32) {
            float sg[4];
            #pragma unroll
            for (int g = 0; g < 4; ++g) {
                float s = bias_g[g];
                #pragma unroll
                for (int k2 = 0; k2 < 8; ++k2)
                    s += red_s[RBOFF + k2 * RS1 + eb * RS2 + g * 16 + ejj];
                sg[g] = s;
            }
            float cn = sigf(sg[1]) * c_reg + sigf(sg[0]) * tanhf(sg[2]);
            float hn = sigf(sg[3]) * tanhf(cn);
            c_reg = cn;
            p_s[32 + lane] = hn * wz_r;
            __hip_atomic_store(
                hbuf + (parOut + bB0 + eb) * HH + j0 + ejj,
                packh((unsigned)(t + 1), hn),
                __ATOMIC_RELAXED, __HIP_MEMORY_SCOPE_AGENT);
        }
    }

    // final part-sums (t = TT-1)
    __syncthreads();
    if (wv == 2 && lane < 2) {
        float s = 0.f;
        #pragma unroll
        for (int jj = 0; jj < 16; ++jj) s += p_s[lane * 16 + jj];
        part[((size_t)(TT - 1) * PJ + js) * NB + bA0 + lane] = s;
    }
    if (wv == 3 && lane < 2) {
        float s = 0.f;
        #pragma unroll
        for (int jj = 0; jj < 16; ++jj) s += p_s[32 + lane * 16 + jj];
        part[((size_t)(TT - 1) * PJ + js) * NB + bB0 + lane] = s;
    }
}

__global__ void pz_kernel(const float* __restrict__ part,
                          const float* __restrict__ noise,
                          const float* __restrict__ b_z,
                          float* __restrict__ out)
{
    int idx = blockIdx.x * blockDim.x + threadIdx.x;  // t*64 + b
    if (idx >= TT * NB) return;
    int t = idx >> 6, b = idx & 63;
    float s = b_z[0];
    #pragma unroll
    for (int jg = 0; jg < PJ; ++jg) s += part[(t * PJ + jg) * NB + b];
    float pz = 1.f / (1.f + expf(-s));
    out[idx] = pz;
    out[TT * NB + idx] = (noise[idx] < pz) ? 1.f : 0.f;
}

// One block per batch column: stable compaction of tokens where z==1.
__global__ void compact_kernel(const int* __restrict__ sent,
                               const float* __restrict__ zbuf,
                               float* __restrict__ rat,
                               float* __restrict__ zsz)
{
    __shared__ float rat_s[TT];
    __shared__ int scan_s[256];
    int b = blockIdx.x, tid = threadIdx.x;
    int zloc[8];
    int base = tid * 8;
    int c = 0;
    #pragma unroll
    for (int i = 0; i < 8; ++i) {
        zloc[i] = (zbuf[(base + i) * NB + b] != 0.f) ? 1 : 0;
        c += zloc[i];
    }
    scan_s[tid] = c;
    for (int i = tid; i < TT; i += 256) rat_s[i] = 0.f;
    __syncthreads();
    for (int off = 1; off < 256; off <<= 1) {
        int v = scan_s[tid];
        int add = (tid >= off) ? scan_s[tid - off] : 0;
        __syncthreads();
        scan_s[tid] = v + add;
        __syncthreads();
    }
    int total = scan_s[255];
    int pos = scan_s[tid] - c;  // exclusive prefix
    #pragma unroll
    for (int i = 0; i < 8; ++i) {
        if (zloc[i]) { rat_s[pos] = (float)sent[(base + i) * NB + b]; ++pos; }
    }
    __syncthreads();
    for (int i = tid; i < TT; i += 256) rat[i * NB + b] = rat_s[i];
    if (tid == 0) zsz[b] = (float)total;
}

extern "C" void kernel_launch(void* const* d_in, const int* in_sizes, int n_in,
                              void* d_out, int out_size, void* d_ws, size_t ws_size,
                              hipStream_t stream)
{
    const int*   sent  = (const int*)d_in[0];
    const float* noise = (const float*)d_in[1];
    const float* emb   = (const float*)d_in[2];
    const float* W_ih  = (const float*)d_in[3];
    const float* W_hh  = (const float*)d_in[4];
    const float* b_ih  = (const float*)d_in[5];
    const float* b_hh  = (const float*)d_in[6];
    const float* W_z   = (const float*)d_in[7];
    const float* b_z   = (const float*)d_in[8];
    float* out = (float*)d_out;

    char* ws = (char*)d_ws;
    unsigned long long* hbuf = (unsigned long long*)ws;     // 2*64*256*8 = 256 KB
    float* part = (float*)(ws + 262144);                    // 2048*16*64*4 = 8 MB

    // tags must start != any expected tag (1..2048)
    (void)hipMemsetAsync(hbuf, 0, 2 * NB * HH * sizeof(unsigned long long), stream);

    // ~30KB static + 64KB dynamic -> ~94KB -> exactly 1 WG/CU
    lstm_kernel<<<256, 512, 65536, stream>>>(sent, emb, W_ih, W_hh, b_ih, b_hh,
                                             W_z, hbuf, part);
    pz_kernel<<<(TT * NB) / 256, 256, 0, stream>>>(part, noise, b_z, out);
    compact_kernel<<<NB, 256, 0, stream>>>(sent, out + TT * NB,
                                           out + 2 * TT * NB, out + 3 * TT * NB);
}